// Round 4
// baseline (196.905 us; speedup 1.0000x reference)
//
#include <hip/hip_runtime.h>
#include <hip/hip_bf16.h>
#include <math.h>

#define HDIM 150

typedef __bf16 bf16x8 __attribute__((ext_vector_type(8)));
typedef __bf16 bf16x4 __attribute__((ext_vector_type(4)));
typedef float  f32x4  __attribute__((ext_vector_type(4)));

// ---------------------------------------------------------------------------
// Kernel 1: per-read MLP via bf16 MFMA with register-relay layer1->layer2.
// Hidden units are PERMUTED across layer-1 A-tiles so the packed C/D output
// of tile pair (2kt, 2kt+1) is exactly the layer-2 B-fragment for kt:
//   tile 2kt   row (4q+r) = hidden 32kt+8q+r     (j=0..3 of B2)
//   tile 2kt+1 row (4q+r) = hidden 32kt+8q+4+r   (j=4..7 of B2)
// No LDS / shuffles / barriers in the main loop. No software prefetch
// (R3 post-mortem: +16 regs -> scratch spills, WRITE_SIZE 16->30 MB).
// T=4 iters/wave -> 256 reads/block -> grid 4096 (16 blocks/CU of work).
// ---------------------------------------------------------------------------
__global__ __launch_bounds__(256, 4) void k_readmlp(
    const float* __restrict__ x, const int* __restrict__ kmer,
    const float* __restrict__ emb, const float* __restrict__ W1,
    const float* __restrict__ b1, const float* __restrict__ W2,
    const float* __restrict__ b2, __bf16* __restrict__ h, int Ntot)
{
    __shared__ float sW[4050];   // W1 [18][150] | b1 @2700 | W2 [150][8] @2850

    const int tid  = threadIdx.x;
    const int lane = tid & 63;
    const int wv   = tid >> 6;
    const int m    = lane & 15;
    const int q    = lane >> 4;

    for (int e = tid; e < 2700; e += 256) sW[e] = W1[e];
    for (int e = tid; e < 150;  e += 256) sW[2700 + e] = b1[e];
    for (int e = tid; e < 1200; e += 256) sW[2850 + e] = W2[e];
    __syncthreads();

    // layer-1 A-fragments with permuted hidden rows; k==18 row carries b1.
    bf16x8 fA1[10];
#pragma unroll
    for (int n = 0; n < 10; ++n) {
        int hid = 32 * (n >> 1) + 8 * (m >> 2) + 4 * (n & 1) + (m & 3);
#pragma unroll
        for (int j = 0; j < 8; ++j) {
            int k = q * 8 + j;
            float v = 0.f;
            if (hid < HDIM) {
                if (k < 18)       v = sW[k * HDIM + hid];
                else if (k == 18) v = sW[2700 + hid];
            }
            fA1[n][j] = (__bf16)v;
        }
    }
    // layer-2 A: A2[m=p][k=hidden logical], rows m>=8 and k>=150 zero.
    bf16x8 fA2[5];
#pragma unroll
    for (int kt = 0; kt < 5; ++kt) {
#pragma unroll
        for (int j = 0; j < 8; ++j) {
            int k = kt * 32 + q * 8 + j;
            float v = 0.f;
            if (m < 8 && k < HDIM) v = sW[2850 + k * 8 + m];
            fA2[kt][j] = (__bf16)v;
        }
    }
    float4 breg = *(const float4*)(b2 + (q & 1) * 4);

    const float4* x4   = (const float4*)x;
    const float2* emb2 = (const float2*)emb;
    const int waveBase = blockIdx.x * 256 + wv * 64;
    const f32x4 zero = {0.f, 0.f, 0.f, 0.f};

    for (int t = 0; t < 4; ++t) {
        int r  = waveBase + t * 16 + m;
        int rc = r < Ntot ? r : (Ntot - 1);

        // input B-fragment: B[k = q*8+j][n = read m]
        bf16x8 bin;
        if (q < 2) {
            float4 u0 = x4[(size_t)rc * 4 + q * 2];
            float4 u1 = x4[(size_t)rc * 4 + q * 2 + 1];
            bin[0] = (__bf16)u0.x; bin[1] = (__bf16)u0.y;
            bin[2] = (__bf16)u0.z; bin[3] = (__bf16)u0.w;
            bin[4] = (__bf16)u1.x; bin[5] = (__bf16)u1.y;
            bin[6] = (__bf16)u1.z; bin[7] = (__bf16)u1.w;
        } else if (q == 2) {
            float2 e2 = emb2[kmer[rc]];
            bin[0] = (__bf16)e2.x; bin[1] = (__bf16)e2.y;
            bin[2] = (__bf16)1.0f;   // bias-1 input at k==18
            bin[3] = (__bf16)0.f; bin[4] = (__bf16)0.f;
            bin[5] = (__bf16)0.f; bin[6] = (__bf16)0.f; bin[7] = (__bf16)0.f;
        } else {
#pragma unroll
            for (int j = 0; j < 8; ++j) bin[j] = (__bf16)0.f;
        }

        // layer1 tile-pair -> relu/pack -> layer2, all in registers.
        // Two independent layer-2 accumulator chains (even/odd kt) for ILP.
        f32x4 c2a = zero, c2b = zero;
#pragma unroll
        for (int kt = 0; kt < 5; ++kt) {
            f32x4 ca = __builtin_amdgcn_mfma_f32_16x16x32_bf16(fA1[2 * kt],     bin, zero, 0, 0, 0);
            f32x4 cb = __builtin_amdgcn_mfma_f32_16x16x32_bf16(fA1[2 * kt + 1], bin, zero, 0, 0, 0);
            bf16x8 bh;
            bh[0] = (__bf16)fmaxf(ca[0], 0.f); bh[1] = (__bf16)fmaxf(ca[1], 0.f);
            bh[2] = (__bf16)fmaxf(ca[2], 0.f); bh[3] = (__bf16)fmaxf(ca[3], 0.f);
            bh[4] = (__bf16)fmaxf(cb[0], 0.f); bh[5] = (__bf16)fmaxf(cb[1], 0.f);
            bh[6] = (__bf16)fmaxf(cb[2], 0.f); bh[7] = (__bf16)fmaxf(cb[3], 0.f);
            if (kt & 1) c2b = __builtin_amdgcn_mfma_f32_16x16x32_bf16(fA2[kt], bh, c2b, 0, 0, 0);
            else        c2a = __builtin_amdgcn_mfma_f32_16x16x32_bf16(fA2[kt], bh, c2a, 0, 0, 0);
        }

        if (q < 2 && r < Ntot) {
            bf16x4 o;
            o[0] = (__bf16)fmaxf(c2a[0] + c2b[0] + breg.x, 0.f);
            o[1] = (__bf16)fmaxf(c2a[1] + c2b[1] + breg.y, 0.f);
            o[2] = (__bf16)fmaxf(c2a[2] + c2b[2] + breg.z, 0.f);
            o[3] = (__bf16)fmaxf(c2a[3] + c2b[3] + breg.w, 0.f);
            *(bf16x4*)(h + (size_t)r * 8 + q * 4) = o;
        }
    }
}

// ---------------------------------------------------------------------------
// fully unrolled Batcher odd-even mergesort, n = 32
// ---------------------------------------------------------------------------
__device__ __forceinline__ void cswap(float& a, float& b) {
    float lo = fminf(a, b);
    float hi = fmaxf(a, b);
    a = lo; b = hi;
}

__device__ __forceinline__ void sort32(float v[32]) {
#pragma unroll
    for (int pp = 1; pp < 32; pp <<= 1) {
#pragma unroll
        for (int k = pp; k >= 1; k >>= 1) {
#pragma unroll
            for (int j = k & (pp - 1); j + k < 32; j += 2 * k) {
#pragma unroll
                for (int i = 0; i < k; ++i) {
                    if ((i + j) / (2 * pp) == (i + j + k) / (2 * pp))
                        cswap(v[i + j], v[i + j + k]);
                }
            }
        }
    }
}

// ---------------------------------------------------------------------------
// Kernel 2: per-site aggregation + head MLP. (unchanged from R3 on purpose:
// once k1 drops below it, its real duration appears in the top-5.)
// ---------------------------------------------------------------------------
__global__ __launch_bounds__(256) void k_site(
    const __bf16* __restrict__ hb, const int* __restrict__ indices,
    const float* __restrict__ W3, const float* __restrict__ b3,
    const float* __restrict__ W4, const float* __restrict__ b4,
    float* __restrict__ out, int Gtot)
{
    __shared__ int   sIdx[32 * 33];     // 4.2 KB
    __shared__ float sW3T[HDIM * 44];   // 26.4 KB, row j = W3[:,j], pitch 44
    __shared__ float sB3[HDIM];
    __shared__ float sW4[HDIM];
    __shared__ float sAgg[32 * 44];     // 5.6 KB, [group][40] pitch 44

    const int tid  = threadIdx.x;
    const int gblk = blockIdx.x * 32;

    for (int e = tid; e < 1024; e += 256) {
        int g = e >> 5;
        sIdx[g * 33 + (e & 31)] = (gblk + g < Gtot) ? indices[(size_t)gblk * 32 + e] : 0;
    }
    for (int e = tid; e < 40 * HDIM; e += 256) {
        int c = e / HDIM, j = e - c * HDIM;    // W3 row-major [40][150]
        sW3T[j * 44 + c] = W3[e];
    }
    for (int e = tid; e < HDIM; e += 256) { sB3[e] = b3[e]; sW4[e] = W4[e]; }
    __syncthreads();

    const int g = tid >> 3, p = tid & 7;
    {
        float v[32];
#pragma unroll
        for (int mm = 0; mm < 32; ++mm) {
            int r = sIdx[g * 33 + mm];
            v[mm] = (float)hb[(size_t)r * 8 + p];
        }
        float sum = 0.f, sumsq = 0.f, mn = v[0], mx = v[0];
#pragma unroll
        for (int mm = 0; mm < 32; ++mm) {
            sum += v[mm];
            sumsq = fmaf(v[mm], v[mm], sumsq);
            mn = fminf(mn, v[mm]);
            mx = fmaxf(mx, v[mm]);
        }
        float mean = sum * (1.f / 32.f);
        float var  = fmaxf((sumsq - 32.f * mean * mean) * (1.f / 31.f), 0.f);
        sort32(v);
        sAgg[g * 44 + 0 * 8 + p] = mean;
        sAgg[g * 44 + 1 * 8 + p] = var;
        sAgg[g * 44 + 2 * 8 + p] = mn;
        sAgg[g * 44 + 3 * 8 + p] = v[15];   // lower median
        sAgg[g * 44 + 4 * 8 + p] = mx;
    }
    __syncthreads();

    float ag[40];
#pragma unroll
    for (int c4 = 0; c4 < 10; ++c4) {
        float4 tq = *(const float4*)(sAgg + g * 44 + c4 * 4);
        ag[c4 * 4 + 0] = tq.x; ag[c4 * 4 + 1] = tq.y;
        ag[c4 * 4 + 2] = tq.z; ag[c4 * 4 + 3] = tq.w;
    }

    float acc = 0.f;
    for (int j = p; j < HDIM; j += 8) {
        const float* wr = sW3T + j * 44;
        float z = sB3[j];
#pragma unroll
        for (int c4 = 0; c4 < 10; ++c4) {
            float4 w = *(const float4*)(wr + c4 * 4);
            z = fmaf(ag[c4 * 4 + 0], w.x, z);
            z = fmaf(ag[c4 * 4 + 1], w.y, z);
            z = fmaf(ag[c4 * 4 + 2], w.z, z);
            z = fmaf(ag[c4 * 4 + 3], w.w, z);
        }
        z = fmaxf(z, 0.f);
        acc = fmaf(z, sW4[j], acc);
    }
    acc += __shfl_xor(acc, 1);
    acc += __shfl_xor(acc, 2);
    acc += __shfl_xor(acc, 4);

    if (p == 0 && gblk + g < Gtot) {
        float zf = acc + b4[0];
        out[gblk + g] = 1.f / (1.f + expf(-zf));
    }
}

// ---------------------------------------------------------------------------
extern "C" void kernel_launch(void* const* d_in, const int* in_sizes, int n_in,
                              void* d_out, int out_size, void* d_ws, size_t ws_size,
                              hipStream_t stream) {
    const float* x       = (const float*)d_in[0];
    const int*   kmer    = (const int*)  d_in[1];
    const int*   indices = (const int*)  d_in[2];
    const float* emb     = (const float*)d_in[3];
    const float* W1      = (const float*)d_in[4];
    const float* b1      = (const float*)d_in[5];
    const float* W2      = (const float*)d_in[6];
    const float* b2      = (const float*)d_in[7];
    const float* W3      = (const float*)d_in[8];
    const float* b3      = (const float*)d_in[9];
    const float* W4      = (const float*)d_in[10];
    const float* b4      = (const float*)d_in[11];

    float*  out = (float*)d_out;
    __bf16* h   = (__bf16*)d_ws;          // [N, 8] bf16 = 16 MB

    const int N = in_sizes[1];
    const int G = out_size;

    const int grid1 = (N + 255) / 256;    // 256 reads / block (4 waves x 4 x 16)
    k_readmlp<<<grid1, 256, 0, stream>>>(x, kmer, emb, W1, b1, W2, b2, h, N);

    const int grid2 = (G + 31) / 32;
    k_site<<<grid2, 256, 0, stream>>>(h, indices, W3, b3, W4, b4, out, G);
}

// Round 5
// 180.272 us; speedup vs baseline: 1.0923x; 1.0923x over previous
//
#include <hip/hip_runtime.h>
#include <hip/hip_bf16.h>
#include <math.h>

#define HDIM 150

typedef __bf16 bf16x8 __attribute__((ext_vector_type(8)));
typedef __bf16 bf16x4 __attribute__((ext_vector_type(4)));
typedef float  f32x4  __attribute__((ext_vector_type(4)));

// ---------------------------------------------------------------------------
// Kernel 1: per-read MLP via bf16 MFMA with register-relay layer1->layer2.
// Hidden units are PERMUTED across layer-1 A-tiles so the packed C/D output
// of tile pair (2kt, 2kt+1) is exactly the layer-2 B-fragment for kt:
//   tile 2kt   row (4q+r) = hidden 32kt+8q+r     (j=0..3 of B2)
//   tile 2kt+1 row (4q+r) = hidden 32kt+8q+4+r   (j=4..7 of B2)
// No LDS / shuffles / barriers in the main loop.
// R4 post-mortem: __launch_bounds__(256,4) capped the unified VGPR file at
// 128/wave -> the ~110-reg live set spilled to scratch (WRITE_SIZE 61 MB).
// Fix: (256,2) -> 256-VGPR ceiling, zero spill; ILP (unrolled T=8 iters,
// dual MFMA chains) hides latency instead of occupancy.
// ---------------------------------------------------------------------------
__global__ __launch_bounds__(256, 2) void k_readmlp(
    const float* __restrict__ x, const int* __restrict__ kmer,
    const float* __restrict__ emb, const float* __restrict__ W1,
    const float* __restrict__ b1, const float* __restrict__ W2,
    const float* __restrict__ b2, __bf16* __restrict__ h, int Ntot)
{
    __shared__ float sW[4050];   // W1 [18][150] | b1 @2700 | W2 [150][8] @2850

    const int tid  = threadIdx.x;
    const int lane = tid & 63;
    const int wv   = tid >> 6;
    const int m    = lane & 15;
    const int q    = lane >> 4;

    for (int e = tid; e < 2700; e += 256) sW[e] = W1[e];
    for (int e = tid; e < 150;  e += 256) sW[2700 + e] = b1[e];
    for (int e = tid; e < 1200; e += 256) sW[2850 + e] = W2[e];
    __syncthreads();

    // layer-1 A-fragments with permuted hidden rows; k==18 row carries b1.
    bf16x8 fA1[10];
#pragma unroll
    for (int n = 0; n < 10; ++n) {
        int hid = 32 * (n >> 1) + 8 * (m >> 2) + 4 * (n & 1) + (m & 3);
#pragma unroll
        for (int j = 0; j < 8; ++j) {
            int k = q * 8 + j;
            float v = 0.f;
            if (hid < HDIM) {
                if (k < 18)       v = sW[k * HDIM + hid];
                else if (k == 18) v = sW[2700 + hid];
            }
            fA1[n][j] = (__bf16)v;
        }
    }
    // layer-2 A: A2[m=p][k=hidden logical], rows m>=8 and k>=150 zero.
    bf16x8 fA2[5];
#pragma unroll
    for (int kt = 0; kt < 5; ++kt) {
#pragma unroll
        for (int j = 0; j < 8; ++j) {
            int k = kt * 32 + q * 8 + j;
            float v = 0.f;
            if (m < 8 && k < HDIM) v = sW[2850 + k * 8 + m];
            fA2[kt][j] = (__bf16)v;
        }
    }
    float4 breg = *(const float4*)(b2 + (q & 1) * 4);

    const float4* x4   = (const float4*)x;
    const float2* emb2 = (const float2*)emb;
    const int waveBase = blockIdx.x * 512 + wv * 128;
    const f32x4 zero = {0.f, 0.f, 0.f, 0.f};

#pragma unroll
    for (int t = 0; t < 8; ++t) {
        int r  = waveBase + t * 16 + m;
        int rc = r < Ntot ? r : (Ntot - 1);

        // input B-fragment: B[k = q*8+j][n = read m]
        bf16x8 bin;
        if (q < 2) {
            float4 u0 = x4[(size_t)rc * 4 + q * 2];
            float4 u1 = x4[(size_t)rc * 4 + q * 2 + 1];
            bin[0] = (__bf16)u0.x; bin[1] = (__bf16)u0.y;
            bin[2] = (__bf16)u0.z; bin[3] = (__bf16)u0.w;
            bin[4] = (__bf16)u1.x; bin[5] = (__bf16)u1.y;
            bin[6] = (__bf16)u1.z; bin[7] = (__bf16)u1.w;
        } else if (q == 2) {
            float2 e2 = emb2[kmer[rc]];
            bin[0] = (__bf16)e2.x; bin[1] = (__bf16)e2.y;
            bin[2] = (__bf16)1.0f;   // bias-1 input at k==18
            bin[3] = (__bf16)0.f; bin[4] = (__bf16)0.f;
            bin[5] = (__bf16)0.f; bin[6] = (__bf16)0.f; bin[7] = (__bf16)0.f;
        } else {
#pragma unroll
            for (int j = 0; j < 8; ++j) bin[j] = (__bf16)0.f;
        }

        // layer1 tile-pair -> relu/pack -> layer2, all in registers.
        // Two independent layer-2 accumulator chains (even/odd kt) for ILP.
        f32x4 c2a = zero, c2b = zero;
#pragma unroll
        for (int kt = 0; kt < 5; ++kt) {
            f32x4 ca = __builtin_amdgcn_mfma_f32_16x16x32_bf16(fA1[2 * kt],     bin, zero, 0, 0, 0);
            f32x4 cb = __builtin_amdgcn_mfma_f32_16x16x32_bf16(fA1[2 * kt + 1], bin, zero, 0, 0, 0);
            bf16x8 bh;
            bh[0] = (__bf16)fmaxf(ca[0], 0.f); bh[1] = (__bf16)fmaxf(ca[1], 0.f);
            bh[2] = (__bf16)fmaxf(ca[2], 0.f); bh[3] = (__bf16)fmaxf(ca[3], 0.f);
            bh[4] = (__bf16)fmaxf(cb[0], 0.f); bh[5] = (__bf16)fmaxf(cb[1], 0.f);
            bh[6] = (__bf16)fmaxf(cb[2], 0.f); bh[7] = (__bf16)fmaxf(cb[3], 0.f);
            if (kt & 1) c2b = __builtin_amdgcn_mfma_f32_16x16x32_bf16(fA2[kt], bh, c2b, 0, 0, 0);
            else        c2a = __builtin_amdgcn_mfma_f32_16x16x32_bf16(fA2[kt], bh, c2a, 0, 0, 0);
        }

        if (q < 2 && r < Ntot) {
            bf16x4 o;
            o[0] = (__bf16)fmaxf(c2a[0] + c2b[0] + breg.x, 0.f);
            o[1] = (__bf16)fmaxf(c2a[1] + c2b[1] + breg.y, 0.f);
            o[2] = (__bf16)fmaxf(c2a[2] + c2b[2] + breg.z, 0.f);
            o[3] = (__bf16)fmaxf(c2a[3] + c2b[3] + breg.w, 0.f);
            *(bf16x4*)(h + (size_t)r * 8 + q * 4) = o;
        }
    }
}

// ---------------------------------------------------------------------------
// fully unrolled Batcher odd-even mergesort, n = 32
// ---------------------------------------------------------------------------
__device__ __forceinline__ void cswap(float& a, float& b) {
    float lo = fminf(a, b);
    float hi = fmaxf(a, b);
    a = lo; b = hi;
}

__device__ __forceinline__ void sort32(float v[32]) {
#pragma unroll
    for (int pp = 1; pp < 32; pp <<= 1) {
#pragma unroll
        for (int k = pp; k >= 1; k >>= 1) {
#pragma unroll
            for (int j = k & (pp - 1); j + k < 32; j += 2 * k) {
#pragma unroll
                for (int i = 0; i < k; ++i) {
                    if ((i + j) / (2 * pp) == (i + j + k) / (2 * pp))
                        cswap(v[i + j], v[i + j + k]);
                }
            }
        }
    }
}

// ---------------------------------------------------------------------------
// Kernel 2: per-site aggregation + head MLP. (unchanged: with k1 fixed it
// will surface in the top-5 and get its first real measurement.)
// ---------------------------------------------------------------------------
__global__ __launch_bounds__(256) void k_site(
    const __bf16* __restrict__ hb, const int* __restrict__ indices,
    const float* __restrict__ W3, const float* __restrict__ b3,
    const float* __restrict__ W4, const float* __restrict__ b4,
    float* __restrict__ out, int Gtot)
{
    __shared__ int   sIdx[32 * 33];     // 4.2 KB
    __shared__ float sW3T[HDIM * 44];   // 26.4 KB, row j = W3[:,j], pitch 44
    __shared__ float sB3[HDIM];
    __shared__ float sW4[HDIM];
    __shared__ float sAgg[32 * 44];     // 5.6 KB, [group][40] pitch 44

    const int tid  = threadIdx.x;
    const int gblk = blockIdx.x * 32;

    for (int e = tid; e < 1024; e += 256) {
        int g = e >> 5;
        sIdx[g * 33 + (e & 31)] = (gblk + g < Gtot) ? indices[(size_t)gblk * 32 + e] : 0;
    }
    for (int e = tid; e < 40 * HDIM; e += 256) {
        int c = e / HDIM, j = e - c * HDIM;    // W3 row-major [40][150]
        sW3T[j * 44 + c] = W3[e];
    }
    for (int e = tid; e < HDIM; e += 256) { sB3[e] = b3[e]; sW4[e] = W4[e]; }
    __syncthreads();

    const int g = tid >> 3, p = tid & 7;
    {
        float v[32];
#pragma unroll
        for (int mm = 0; mm < 32; ++mm) {
            int r = sIdx[g * 33 + mm];
            v[mm] = (float)hb[(size_t)r * 8 + p];
        }
        float sum = 0.f, sumsq = 0.f, mn = v[0], mx = v[0];
#pragma unroll
        for (int mm = 0; mm < 32; ++mm) {
            sum += v[mm];
            sumsq = fmaf(v[mm], v[mm], sumsq);
            mn = fminf(mn, v[mm]);
            mx = fmaxf(mx, v[mm]);
        }
        float mean = sum * (1.f / 32.f);
        float var  = fmaxf((sumsq - 32.f * mean * mean) * (1.f / 31.f), 0.f);
        sort32(v);
        sAgg[g * 44 + 0 * 8 + p] = mean;
        sAgg[g * 44 + 1 * 8 + p] = var;
        sAgg[g * 44 + 2 * 8 + p] = mn;
        sAgg[g * 44 + 3 * 8 + p] = v[15];   // lower median
        sAgg[g * 44 + 4 * 8 + p] = mx;
    }
    __syncthreads();

    float ag[40];
#pragma unroll
    for (int c4 = 0; c4 < 10; ++c4) {
        float4 tq = *(const float4*)(sAgg + g * 44 + c4 * 4);
        ag[c4 * 4 + 0] = tq.x; ag[c4 * 4 + 1] = tq.y;
        ag[c4 * 4 + 2] = tq.z; ag[c4 * 4 + 3] = tq.w;
    }

    float acc = 0.f;
    for (int j = p; j < HDIM; j += 8) {
        const float* wr = sW3T + j * 44;
        float z = sB3[j];
#pragma unroll
        for (int c4 = 0; c4 < 10; ++c4) {
            float4 w = *(const float4*)(wr + c4 * 4);
            z = fmaf(ag[c4 * 4 + 0], w.x, z);
            z = fmaf(ag[c4 * 4 + 1], w.y, z);
            z = fmaf(ag[c4 * 4 + 2], w.z, z);
            z = fmaf(ag[c4 * 4 + 3], w.w, z);
        }
        z = fmaxf(z, 0.f);
        acc = fmaf(z, sW4[j], acc);
    }
    acc += __shfl_xor(acc, 1);
    acc += __shfl_xor(acc, 2);
    acc += __shfl_xor(acc, 4);

    if (p == 0 && gblk + g < Gtot) {
        float zf = acc + b4[0];
        out[gblk + g] = 1.f / (1.f + expf(-zf));
    }
}

// ---------------------------------------------------------------------------
extern "C" void kernel_launch(void* const* d_in, const int* in_sizes, int n_in,
                              void* d_out, int out_size, void* d_ws, size_t ws_size,
                              hipStream_t stream) {
    const float* x       = (const float*)d_in[0];
    const int*   kmer    = (const int*)  d_in[1];
    const int*   indices = (const int*)  d_in[2];
    const float* emb     = (const float*)d_in[3];
    const float* W1      = (const float*)d_in[4];
    const float* b1      = (const float*)d_in[5];
    const float* W2      = (const float*)d_in[6];
    const float* b2      = (const float*)d_in[7];
    const float* W3      = (const float*)d_in[8];
    const float* b3      = (const float*)d_in[9];
    const float* W4      = (const float*)d_in[10];
    const float* b4      = (const float*)d_in[11];

    float*  out = (float*)d_out;
    __bf16* h   = (__bf16*)d_ws;          // [N, 8] bf16 = 16 MB

    const int N = in_sizes[1];
    const int G = out_size;

    const int grid1 = (N + 511) / 512;    // 512 reads / block (4 waves x 8 x 16)
    k_readmlp<<<grid1, 256, 0, stream>>>(x, kmer, emb, W1, b1, W2, b2, h, N);

    const int grid2 = (G + 31) / 32;
    k_site<<<grid2, 256, 0, stream>>>(h, indices, W3, b3, W4, b4, out, G);
}

// Round 6
// 170.279 us; speedup vs baseline: 1.1564x; 1.0587x over previous
//
#include <hip/hip_runtime.h>
#include <hip/hip_bf16.h>
#include <math.h>

#define HDIM 150
#define T1 8          // x-tiles (of 16 reads) per wave

typedef __bf16 bf16x8 __attribute__((ext_vector_type(8)));
typedef __bf16 bf16x4 __attribute__((ext_vector_type(4)));
typedef float  f32x4  __attribute__((ext_vector_type(4)));

__device__ __forceinline__ void async_copy16(const void* g, void* l) {
    __builtin_amdgcn_global_load_lds(
        (const __attribute__((address_space(1))) void*)g,
        (__attribute__((address_space(3))) void*)l, 16, 0, 0);
}

// ---------------------------------------------------------------------------
// Kernel 1: per-read MLP via bf16 MFMA, register-relay layer1->layer2.
// R5 post-mortem: per-iter dependent global loads at 2 waves/SIMD = pure
// latency bound (700 GB/s, VALU 30%, MFMA 8%). Fix: pay latency ONCE per
// wave — 8x global_load_lds (16B/lane, 1KB/tile) issued up front into
// wave-private LDS; single vmcnt drain; then 8 iters of LDS-fed MFMA.
// Global-side XOR granule swizzle makes the b128 fragment reads
// bank-balanced (DMA lane->LDS mapping is fixed; we permute gaddr instead).
// emb values for the wave's 128 reads live in 4 VGPRs, delivered by shfl.
// h outputs accumulated in regs, stored after the loop.
// ---------------------------------------------------------------------------
__global__ __launch_bounds__(256, 3) void k_readmlp(
    const float* __restrict__ x, const int* __restrict__ kmer,
    const float* __restrict__ emb, const float* __restrict__ W1,
    const float* __restrict__ b1, const float* __restrict__ W2,
    const float* __restrict__ b2, __bf16* __restrict__ h, int Ntot)
{
    // union: weight staging (16.2 KB) then 4 waves x 8 KB x-tile buffers
    __shared__ __align__(16) char smem[32768];
    float* sW = (float*)smem;    // W1 [18][150] | b1 @2700 | W2 [150][8] @2850

    const int tid  = threadIdx.x;
    const int lane = tid & 63;
    const int wv   = tid >> 6;
    const int m    = lane & 15;
    const int q    = lane >> 4;

    for (int e = tid; e < 2700; e += 256) sW[e] = W1[e];
    for (int e = tid; e < 150;  e += 256) sW[2700 + e] = b1[e];
    for (int e = tid; e < 1200; e += 256) sW[2850 + e] = W2[e];
    __syncthreads();

    // layer-1 A-fragments, hidden rows permuted for the register relay:
    //   tile 2kt   row (4q+r) = hidden 32kt+8q+r
    //   tile 2kt+1 row (4q+r) = hidden 32kt+8q+4+r
    // k==18 row carries b1 (input supplies 1.0).
    bf16x8 fA1[10];
#pragma unroll
    for (int n = 0; n < 10; ++n) {
        int hid = 32 * (n >> 1) + 8 * (m >> 2) + 4 * (n & 1) + (m & 3);
#pragma unroll
        for (int j = 0; j < 8; ++j) {
            int k = q * 8 + j;
            float v = 0.f;
            if (hid < HDIM) {
                if (k < 18)       v = sW[k * HDIM + hid];
                else if (k == 18) v = sW[2700 + hid];
            }
            fA1[n][j] = (__bf16)v;
        }
    }
    // layer-2 A: A2[m=p][k=hidden logical]
    bf16x8 fA2[5];
#pragma unroll
    for (int kt = 0; kt < 5; ++kt) {
#pragma unroll
        for (int j = 0; j < 8; ++j) {
            int k = kt * 32 + q * 8 + j;
            float v = 0.f;
            if (m < 8 && k < HDIM) v = sW[2850 + k * 8 + m];
            fA2[kt][j] = (__bf16)v;
        }
    }
    float4 breg = *(const float4*)(b2 + (q & 1) * 4);
    __syncthreads();   // all waves done reading sW; buffers may be overwritten

    char* xbase = smem + wv * (T1 * 1024);
    const int waveBase = blockIdx.x * 512 + wv * 128;

    // --- issue all 8 x-tile DMAs (lane fetches swizzled granule) ---
    // LDS slot s (16B) of tile t holds global granule g = s ^ ((s>>3)&7).
    const int gsw = lane ^ ((lane >> 3) & 7);
    const size_t xlimit = (size_t)Ntot * 64 - 16;
    const char* xg = (const char*)x;
#pragma unroll
    for (int t = 0; t < T1; ++t) {
        size_t off = (size_t)(waveBase + t * 16) * 64 + (size_t)gsw * 16;
        if (off > xlimit) off = xlimit;
        async_copy16(xg + off, xbase + t * 1024);
    }

    // --- kmer -> emb for this wave's 128 reads, held in registers ---
    const float2* emb2 = (const float2*)emb;
    int i0 = waveBase + lane;      if (i0 >= Ntot) i0 = Ntot - 1;
    int i1 = waveBase + 64 + lane; if (i1 >= Ntot) i1 = Ntot - 1;
    float2 e0 = emb2[kmer[i0]];
    float2 e1 = emb2[kmer[i1]];

    const f32x4 zero = {0.f, 0.f, 0.f, 0.f};
    bf16x4 outs[T1];

#pragma unroll
    for (int t = 0; t < T1; ++t) {
        // emb pair for read (waveBase + 16t + m) via shuffle (t compile-time)
        int src = ((t & 3) << 4) + m;
        float ex = __shfl(t < 4 ? e0.x : e1.x, src);
        float ey = __shfl(t < 4 ? e0.y : e1.y, src);

        // input B-fragment: B[k = q*8+j][n = read m]
        bf16x8 bin;
        if (q < 2) {
            int g0 = 4 * m + 2 * q;             // granules for floats 8q..8q+7
            int sx = (g0 >> 3) & 7;
            const char* tb = xbase + t * 1024;
            f32x4 u0 = *(const f32x4*)(tb + ((g0     ^ sx) << 4));
            f32x4 u1 = *(const f32x4*)(tb + (((g0 + 1) ^ sx) << 4));
            bin[0] = (__bf16)u0[0]; bin[1] = (__bf16)u0[1];
            bin[2] = (__bf16)u0[2]; bin[3] = (__bf16)u0[3];
            bin[4] = (__bf16)u1[0]; bin[5] = (__bf16)u1[1];
            bin[6] = (__bf16)u1[2]; bin[7] = (__bf16)u1[3];
        } else if (q == 2) {
            bin[0] = (__bf16)ex; bin[1] = (__bf16)ey;
            bin[2] = (__bf16)1.0f;   // bias-1 input at k==18
            bin[3] = (__bf16)0.f; bin[4] = (__bf16)0.f;
            bin[5] = (__bf16)0.f; bin[6] = (__bf16)0.f; bin[7] = (__bf16)0.f;
        } else {
#pragma unroll
            for (int j = 0; j < 8; ++j) bin[j] = (__bf16)0.f;
        }

        // layer1 tile-pair -> relu/pack -> layer2, all in registers.
        f32x4 c2a = zero, c2b = zero;
#pragma unroll
        for (int kt = 0; kt < 5; ++kt) {
            f32x4 ca = __builtin_amdgcn_mfma_f32_16x16x32_bf16(fA1[2 * kt],     bin, zero, 0, 0, 0);
            f32x4 cb = __builtin_amdgcn_mfma_f32_16x16x32_bf16(fA1[2 * kt + 1], bin, zero, 0, 0, 0);
            bf16x8 bh;
            bh[0] = (__bf16)fmaxf(ca[0], 0.f); bh[1] = (__bf16)fmaxf(ca[1], 0.f);
            bh[2] = (__bf16)fmaxf(ca[2], 0.f); bh[3] = (__bf16)fmaxf(ca[3], 0.f);
            bh[4] = (__bf16)fmaxf(cb[0], 0.f); bh[5] = (__bf16)fmaxf(cb[1], 0.f);
            bh[6] = (__bf16)fmaxf(cb[2], 0.f); bh[7] = (__bf16)fmaxf(cb[3], 0.f);
            if (kt & 1) c2b = __builtin_amdgcn_mfma_f32_16x16x32_bf16(fA2[kt], bh, c2b, 0, 0, 0);
            else        c2a = __builtin_amdgcn_mfma_f32_16x16x32_bf16(fA2[kt], bh, c2a, 0, 0, 0);
        }
        bf16x4 o;
        o[0] = (__bf16)fmaxf(c2a[0] + c2b[0] + breg.x, 0.f);
        o[1] = (__bf16)fmaxf(c2a[1] + c2b[1] + breg.y, 0.f);
        o[2] = (__bf16)fmaxf(c2a[2] + c2b[2] + breg.z, 0.f);
        o[3] = (__bf16)fmaxf(c2a[3] + c2b[3] + breg.w, 0.f);
        outs[t] = o;
    }

    // --- epilogue: store all tiles (coalesced dwordx2) ---
#pragma unroll
    for (int t = 0; t < T1; ++t) {
        int r = waveBase + t * 16 + m;
        if (q < 2 && r < Ntot)
            *(bf16x4*)(h + (size_t)r * 8 + q * 4) = outs[t];
    }
}

// ---------------------------------------------------------------------------
// fully unrolled Batcher odd-even mergesort, n = 32
// ---------------------------------------------------------------------------
__device__ __forceinline__ void cswap(float& a, float& b) {
    float lo = fminf(a, b);
    float hi = fmaxf(a, b);
    a = lo; b = hi;
}

__device__ __forceinline__ void sort32(float v[32]) {
#pragma unroll
    for (int pp = 1; pp < 32; pp <<= 1) {
#pragma unroll
        for (int k = pp; k >= 1; k >>= 1) {
#pragma unroll
            for (int j = k & (pp - 1); j + k < 32; j += 2 * k) {
#pragma unroll
                for (int i = 0; i < k; ++i) {
                    if ((i + j) / (2 * pp) == (i + j + k) / (2 * pp))
                        cswap(v[i + j], v[i + j + k]);
                }
            }
        }
    }
}

// ---------------------------------------------------------------------------
// Kernel 2: per-site aggregation + head MLP (unchanged; will surface in the
// top-5 now that k1 is fast -> first real measurement).
// ---------------------------------------------------------------------------
__global__ __launch_bounds__(256) void k_site(
    const __bf16* __restrict__ hb, const int* __restrict__ indices,
    const float* __restrict__ W3, const float* __restrict__ b3,
    const float* __restrict__ W4, const float* __restrict__ b4,
    float* __restrict__ out, int Gtot)
{
    __shared__ int   sIdx[32 * 33];     // 4.2 KB
    __shared__ float sW3T[HDIM * 44];   // 26.4 KB, row j = W3[:,j], pitch 44
    __shared__ float sB3[HDIM];
    __shared__ float sW4[HDIM];
    __shared__ float sAgg[32 * 44];     // 5.6 KB, [group][40] pitch 44

    const int tid  = threadIdx.x;
    const int gblk = blockIdx.x * 32;

    for (int e = tid; e < 1024; e += 256) {
        int g = e >> 5;
        sIdx[g * 33 + (e & 31)] = (gblk + g < Gtot) ? indices[(size_t)gblk * 32 + e] : 0;
    }
    for (int e = tid; e < 40 * HDIM; e += 256) {
        int c = e / HDIM, j = e - c * HDIM;    // W3 row-major [40][150]
        sW3T[j * 44 + c] = W3[e];
    }
    for (int e = tid; e < HDIM; e += 256) { sB3[e] = b3[e]; sW4[e] = W4[e]; }
    __syncthreads();

    const int g = tid >> 3, p = tid & 7;
    {
        float v[32];
#pragma unroll
        for (int mm = 0; mm < 32; ++mm) {
            int r = sIdx[g * 33 + mm];
            v[mm] = (float)hb[(size_t)r * 8 + p];
        }
        float sum = 0.f, sumsq = 0.f, mn = v[0], mx = v[0];
#pragma unroll
        for (int mm = 0; mm < 32; ++mm) {
            sum += v[mm];
            sumsq = fmaf(v[mm], v[mm], sumsq);
            mn = fminf(mn, v[mm]);
            mx = fmaxf(mx, v[mm]);
        }
        float mean = sum * (1.f / 32.f);
        float var  = fmaxf((sumsq - 32.f * mean * mean) * (1.f / 31.f), 0.f);
        sort32(v);
        sAgg[g * 44 + 0 * 8 + p] = mean;
        sAgg[g * 44 + 1 * 8 + p] = var;
        sAgg[g * 44 + 2 * 8 + p] = mn;
        sAgg[g * 44 + 3 * 8 + p] = v[15];   // lower median
        sAgg[g * 44 + 4 * 8 + p] = mx;
    }
    __syncthreads();

    float ag[40];
#pragma unroll
    for (int c4 = 0; c4 < 10; ++c4) {
        float4 tq = *(const float4*)(sAgg + g * 44 + c4 * 4);
        ag[c4 * 4 + 0] = tq.x; ag[c4 * 4 + 1] = tq.y;
        ag[c4 * 4 + 2] = tq.z; ag[c4 * 4 + 3] = tq.w;
    }

    float acc = 0.f;
    for (int j = p; j < HDIM; j += 8) {
        const float* wr = sW3T + j * 44;
        float z = sB3[j];
#pragma unroll
        for (int c4 = 0; c4 < 10; ++c4) {
            float4 w = *(const float4*)(wr + c4 * 4);
            z = fmaf(ag[c4 * 4 + 0], w.x, z);
            z = fmaf(ag[c4 * 4 + 1], w.y, z);
            z = fmaf(ag[c4 * 4 + 2], w.z, z);
            z = fmaf(ag[c4 * 4 + 3], w.w, z);
        }
        z = fmaxf(z, 0.f);
        acc = fmaf(z, sW4[j], acc);
    }
    acc += __shfl_xor(acc, 1);
    acc += __shfl_xor(acc, 2);
    acc += __shfl_xor(acc, 4);

    if (p == 0 && gblk + g < Gtot) {
        float zf = acc + b4[0];
        out[gblk + g] = 1.f / (1.f + expf(-zf));
    }
}

// ---------------------------------------------------------------------------
extern "C" void kernel_launch(void* const* d_in, const int* in_sizes, int n_in,
                              void* d_out, int out_size, void* d_ws, size_t ws_size,
                              hipStream_t stream) {
    const float* x       = (const float*)d_in[0];
    const int*   kmer    = (const int*)  d_in[1];
    const int*   indices = (const int*)  d_in[2];
    const float* emb     = (const float*)d_in[3];
    const float* W1      = (const float*)d_in[4];
    const float* b1      = (const float*)d_in[5];
    const float* W2      = (const float*)d_in[6];
    const float* b2      = (const float*)d_in[7];
    const float* W3      = (const float*)d_in[8];
    const float* b3      = (const float*)d_in[9];
    const float* W4      = (const float*)d_in[10];
    const float* b4      = (const float*)d_in[11];

    float*  out = (float*)d_out;
    __bf16* h   = (__bf16*)d_ws;          // [N, 8] bf16 = 16 MB

    const int N = in_sizes[1];
    const int G = out_size;

    const int grid1 = (N + 511) / 512;    // 512 reads / block (4 waves x 8 x 16)
    k_readmlp<<<grid1, 256, 0, stream>>>(x, kmer, emb, W1, b1, W2, b2, h, N);

    const int grid2 = (G + 31) / 32;
    k_site<<<grid2, 256, 0, stream>>>(h, indices, W3, b3, W4, b4, out, G);
}

// Round 7
// 158.637 us; speedup vs baseline: 1.2412x; 1.0734x over previous
//
#include <hip/hip_runtime.h>
#include <hip/hip_bf16.h>
#include <math.h>

#define HDIM 150
#define T1 8          // x-tiles (of 16 reads) per wave in k1

typedef __bf16 bf16x8 __attribute__((ext_vector_type(8)));
typedef __bf16 bf16x4 __attribute__((ext_vector_type(4)));
typedef float  f32x4  __attribute__((ext_vector_type(4)));

__device__ __forceinline__ void async_copy16(const void* g, void* l) {
    __builtin_amdgcn_global_load_lds(
        (const __attribute__((address_space(1))) void*)g,
        (__attribute__((address_space(3))) void*)l, 16, 0, 0);
}

// ---------------------------------------------------------------------------
// k_pack: one block precomputes the per-lane MFMA fragment blob shared by
// every k1 wave (R6 post-mortem: the per-block fragment build was ~500 VALU
// + 2 barriers + 1.5M LDS bank conflicts, paid 2048x).
// Blob layout (uint4 view): tile i of lane L at blob4[i*64 + L]  -> k1's
// reload is lane-coalesced. Per lane: dwords 0..39 = fA1[10] (bf16x8 each),
// 40..59 = fA2[5], 60..63 = breg (f32x4).
// ---------------------------------------------------------------------------
__global__ void k_pack(const float* __restrict__ W1, const float* __restrict__ b1,
                       const float* __restrict__ W2, const float* __restrict__ b2,
                       unsigned int* __restrict__ blob)
{
    const int t    = threadIdx.x;
    const int lane = t & 63;
    const int c    = t >> 6;        // dword chunk 0..3
    const int m    = lane & 15;
    const int q    = lane >> 4;

    for (int d = c * 16; d < c * 16 + 16; ++d) {
        unsigned int word;
        if (d >= 60) {
            word = __float_as_uint(b2[(q & 1) * 4 + (d - 60)]);
        } else {
            float v0 = 0.f, v1 = 0.f;
            if (d < 40) {
                int n = d >> 2, j0 = (d & 3) * 2;
                // permuted hidden rows for the register relay:
                //   tile 2kt   row(4q+r) = hidden 32kt+8q+r
                //   tile 2kt+1 row(4q+r) = hidden 32kt+8q+4+r
                int hid = 32 * (n >> 1) + 8 * (m >> 2) + 4 * (n & 1) + (m & 3);
                if (hid < HDIM) {
                    int k0 = q * 8 + j0, k1 = k0 + 1;
                    v0 = (k0 < 18) ? W1[k0 * HDIM + hid] : (k0 == 18 ? b1[hid] : 0.f);
                    v1 = (k1 < 18) ? W1[k1 * HDIM + hid] : (k1 == 18 ? b1[hid] : 0.f);
                }
            } else {
                int kt = (d - 40) >> 2, j0 = ((d - 40) & 3) * 2;
                int k0 = kt * 32 + q * 8 + j0, k1 = k0 + 1;
                if (m < 8) {
                    v0 = (k0 < HDIM) ? W2[k0 * 8 + m] : 0.f;
                    v1 = (k1 < HDIM) ? W2[k1 * 8 + m] : 0.f;
                }
            }
            __bf16 h0 = (__bf16)v0, h1 = (__bf16)v1;
            unsigned short u0, u1;
            __builtin_memcpy(&u0, &h0, 2);
            __builtin_memcpy(&u1, &h1, 2);
            word = (unsigned int)u0 | ((unsigned int)u1 << 16);
        }
        blob[(d >> 2) * 256 + lane * 4 + (d & 3)] = word;
    }
}

// ---------------------------------------------------------------------------
// Kernel 1: per-read MLP via bf16 MFMA, register-relay layer1->layer2.
// Setup = 16 coalesced b128 loads of the precomputed fragment blob (L2-hot).
// No barriers, no LDS weight staging. x staged per wave via 8x
// global_load_lds (16B/lane) with a global-side XOR granule swizzle so the
// b128 fragment reads are bank-balanced. emb via 2 registers + shfl.
// ---------------------------------------------------------------------------
__global__ __launch_bounds__(256, 3) void k_readmlp(
    const float* __restrict__ x, const int* __restrict__ kmer,
    const float* __restrict__ emb, const unsigned int* __restrict__ blob,
    __bf16* __restrict__ h, int Ntot)
{
    __shared__ __align__(16) char smem[32768];   // 4 waves x 8KB x-tiles

    const int tid  = threadIdx.x;
    const int lane = tid & 63;
    const int wv   = tid >> 6;
    const int m    = lane & 15;
    const int q    = lane >> 4;

    // ---- fragment blob: 16 coalesced dwordx4 loads ----
    uint4 B16[16];
    const uint4* bl = (const uint4*)blob;
#pragma unroll
    for (int i = 0; i < 16; ++i) B16[i] = bl[i * 64 + lane];
    const bf16x8* fr = (const bf16x8*)B16;       // fr[0..9]=fA1, fr[10..14]=fA2
    const float4 breg = ((const float4*)B16)[15];

    char* xbase = smem + wv * (T1 * 1024);
    const int waveBase = blockIdx.x * 512 + wv * 128;

    // ---- issue all 8 x-tile DMAs (lane fetches swizzled granule) ----
    const int gsw = lane ^ ((lane >> 3) & 7);
    const size_t xlimit = (size_t)Ntot * 64 - 16;
    const char* xg = (const char*)x;
#pragma unroll
    for (int t = 0; t < T1; ++t) {
        size_t off = (size_t)(waveBase + t * 16) * 64 + (size_t)gsw * 16;
        if (off > xlimit) off = xlimit;
        async_copy16(xg + off, xbase + t * 1024);
    }

    // ---- kmer -> emb for this wave's 128 reads, in registers ----
    const float2* emb2 = (const float2*)emb;
    int i0 = waveBase + lane;      if (i0 >= Ntot) i0 = Ntot - 1;
    int i1 = waveBase + 64 + lane; if (i1 >= Ntot) i1 = Ntot - 1;
    float2 e0 = emb2[kmer[i0]];
    float2 e1 = emb2[kmer[i1]];

    const f32x4 zero = {0.f, 0.f, 0.f, 0.f};
    bf16x4 outs[T1];

#pragma unroll
    for (int t = 0; t < T1; ++t) {
        int src = ((t & 3) << 4) + m;
        float ex = __shfl(t < 4 ? e0.x : e1.x, src);
        float ey = __shfl(t < 4 ? e0.y : e1.y, src);

        // input B-fragment: B[k = q*8+j][n = read m]
        bf16x8 bin;
        if (q < 2) {
            int g0 = 4 * m + 2 * q;
            int sx = (g0 >> 3) & 7;
            const char* tb = xbase + t * 1024;
            f32x4 u0 = *(const f32x4*)(tb + ((g0       ^ sx) << 4));
            f32x4 u1 = *(const f32x4*)(tb + (((g0 + 1) ^ sx) << 4));
            bin[0] = (__bf16)u0[0]; bin[1] = (__bf16)u0[1];
            bin[2] = (__bf16)u0[2]; bin[3] = (__bf16)u0[3];
            bin[4] = (__bf16)u1[0]; bin[5] = (__bf16)u1[1];
            bin[6] = (__bf16)u1[2]; bin[7] = (__bf16)u1[3];
        } else if (q == 2) {
            bin[0] = (__bf16)ex; bin[1] = (__bf16)ey;
            bin[2] = (__bf16)1.0f;   // bias-1 input at k==18
            bin[3] = (__bf16)0.f; bin[4] = (__bf16)0.f;
            bin[5] = (__bf16)0.f; bin[6] = (__bf16)0.f; bin[7] = (__bf16)0.f;
        } else {
#pragma unroll
            for (int j = 0; j < 8; ++j) bin[j] = (__bf16)0.f;
        }

        // layer1 tile-pair -> relu/pack -> layer2, all in registers.
        f32x4 c2a = zero, c2b = zero;
#pragma unroll
        for (int kt = 0; kt < 5; ++kt) {
            f32x4 ca = __builtin_amdgcn_mfma_f32_16x16x32_bf16(fr[2 * kt],     bin, zero, 0, 0, 0);
            f32x4 cb = __builtin_amdgcn_mfma_f32_16x16x32_bf16(fr[2 * kt + 1], bin, zero, 0, 0, 0);
            bf16x8 bh;
            bh[0] = (__bf16)fmaxf(ca[0], 0.f); bh[1] = (__bf16)fmaxf(ca[1], 0.f);
            bh[2] = (__bf16)fmaxf(ca[2], 0.f); bh[3] = (__bf16)fmaxf(ca[3], 0.f);
            bh[4] = (__bf16)fmaxf(cb[0], 0.f); bh[5] = (__bf16)fmaxf(cb[1], 0.f);
            bh[6] = (__bf16)fmaxf(cb[2], 0.f); bh[7] = (__bf16)fmaxf(cb[3], 0.f);
            if (kt & 1) c2b = __builtin_amdgcn_mfma_f32_16x16x32_bf16(fr[10 + kt], bh, c2b, 0, 0, 0);
            else        c2a = __builtin_amdgcn_mfma_f32_16x16x32_bf16(fr[10 + kt], bh, c2a, 0, 0, 0);
        }
        bf16x4 o;
        o[0] = (__bf16)fmaxf(c2a[0] + c2b[0] + breg.x, 0.f);
        o[1] = (__bf16)fmaxf(c2a[1] + c2b[1] + breg.y, 0.f);
        o[2] = (__bf16)fmaxf(c2a[2] + c2b[2] + breg.z, 0.f);
        o[3] = (__bf16)fmaxf(c2a[3] + c2b[3] + breg.w, 0.f);
        outs[t] = o;
    }

#pragma unroll
    for (int t = 0; t < T1; ++t) {
        int r = waveBase + t * 16 + m;
        if (q < 2 && r < Ntot)
            *(bf16x4*)(h + (size_t)r * 8 + q * 4) = outs[t];
    }
}

// ---------------------------------------------------------------------------
// fully unrolled Batcher odd-even mergesort, n = 32
// ---------------------------------------------------------------------------
__device__ __forceinline__ void cswap(float& a, float& b) {
    float lo = fminf(a, b);
    float hi = fmaxf(a, b);
    a = lo; b = hi;
}

__device__ __forceinline__ void sort32(float v[32]) {
#pragma unroll
    for (int pp = 1; pp < 32; pp <<= 1) {
#pragma unroll
        for (int k = pp; k >= 1; k >>= 1) {
#pragma unroll
            for (int j = k & (pp - 1); j + k < 32; j += 2 * k) {
#pragma unroll
                for (int i = 0; i < k; ++i) {
                    if ((i + j) / (2 * pp) == (i + j + k) / (2 * pp))
                        cswap(v[i + j], v[i + j + k]);
                }
            }
        }
    }
}

// ---------------------------------------------------------------------------
// Kernel 2: per-site aggregation + head MLP.
// R7: gather made cooperative-coalesced — block loads its 1024 h-rows (16B
// each) into LDS sH, then thread (g,p) reads its 32 channel values from LDS
// (p-pairs share a 32-bit word = broadcast; groups hit distinct bank quads).
// W3 tile now bf16 pitch 48 (16B-aligned rows; 24p%32 gives only free 2-way
// aliasing) -> half the LDS-pipe traffic in phase 2, 42KB total = 3 blk/CU.
// ---------------------------------------------------------------------------
__global__ __launch_bounds__(256) void k_site(
    const __bf16* __restrict__ hb, const int* __restrict__ indices,
    const float* __restrict__ W3, const float* __restrict__ b3,
    const float* __restrict__ W4, const float* __restrict__ b4,
    float* __restrict__ out, int Gtot)
{
    __shared__ int    sIdx[32 * 33];        // 4.2 KB
    __shared__ __align__(16) __bf16 sH[32 * 264];  // 16.9 KB: [g][33 rows pad][8ch]
    __shared__ __bf16 sW3B[HDIM * 48];      // 14.4 KB: row j = W3[:,j] bf16, pitch 48
    __shared__ float  sB3[HDIM];
    __shared__ float  sW4[HDIM];
    __shared__ float  sAgg[32 * 44];        // 5.6 KB: [g][40] pitch 44

    const int tid  = threadIdx.x;
    const int gblk = blockIdx.x * 32;

    for (int e = tid; e < 1024; e += 256) {
        int g = e >> 5;
        sIdx[g * 33 + (e & 31)] = (gblk + g < Gtot) ? indices[(size_t)gblk * 32 + e] : 0;
    }
    __syncthreads();

    // cooperative coalesced gather: 4 rounds x 256 lanes x 16B rows
    for (int e = tid; e < 1024; e += 256) {
        int g = e >> 5, mm = e & 31;
        int r = sIdx[g * 33 + mm];
        *(uint4*)(&sH[g * 264 + mm * 8]) = *(const uint4*)(hb + (size_t)r * 8);
    }

    // stage head weights (overlaps gather write latency)
    for (int e = tid; e < 40 * HDIM; e += 256) {
        int c = e / HDIM, j = e - c * HDIM;     // W3 row-major [40][150]
        sW3B[j * 48 + c] = (__bf16)W3[e];
    }
    for (int e = tid; e < HDIM; e += 256) { sB3[e] = b3[e]; sW4[e] = W4[e]; }
    __syncthreads();

    const int g = tid >> 3, p = tid & 7;
    {
        float v[32];
#pragma unroll
        for (int mm = 0; mm < 32; ++mm)
            v[mm] = (float)sH[g * 264 + mm * 8 + p];

        float sum = 0.f, sumsq = 0.f, mn = v[0], mx = v[0];
#pragma unroll
        for (int mm = 0; mm < 32; ++mm) {
            sum += v[mm];
            sumsq = fmaf(v[mm], v[mm], sumsq);
            mn = fminf(mn, v[mm]);
            mx = fmaxf(mx, v[mm]);
        }
        float mean = sum * (1.f / 32.f);
        float var  = fmaxf((sumsq - 32.f * mean * mean) * (1.f / 31.f), 0.f);
        sort32(v);
        sAgg[g * 44 + 0 * 8 + p] = mean;
        sAgg[g * 44 + 1 * 8 + p] = var;
        sAgg[g * 44 + 2 * 8 + p] = mn;
        sAgg[g * 44 + 3 * 8 + p] = v[15];   // lower median
        sAgg[g * 44 + 4 * 8 + p] = mx;
    }
    __syncthreads();

    float ag[40];
#pragma unroll
    for (int c4 = 0; c4 < 10; ++c4) {
        float4 tq = *(const float4*)(sAgg + g * 44 + c4 * 4);
        ag[c4 * 4 + 0] = tq.x; ag[c4 * 4 + 1] = tq.y;
        ag[c4 * 4 + 2] = tq.z; ag[c4 * 4 + 3] = tq.w;
    }

    float acc = 0.f;
    for (int j = p; j < HDIM; j += 8) {
        const __bf16* wr = sW3B + j * 48;
        float z = sB3[j];
#pragma unroll
        for (int c8 = 0; c8 < 5; ++c8) {
            bf16x8 w = *(const bf16x8*)(wr + c8 * 8);
#pragma unroll
            for (int u = 0; u < 8; ++u)
                z = fmaf(ag[c8 * 8 + u], (float)w[u], z);
        }
        z = fmaxf(z, 0.f);
        acc = fmaf(z, sW4[j], acc);
    }
    acc += __shfl_xor(acc, 1);
    acc += __shfl_xor(acc, 2);
    acc += __shfl_xor(acc, 4);

    if (p == 0 && gblk + g < Gtot) {
        float zf = acc + b4[0];
        out[gblk + g] = 1.f / (1.f + expf(-zf));
    }
}

// ---------------------------------------------------------------------------
extern "C" void kernel_launch(void* const* d_in, const int* in_sizes, int n_in,
                              void* d_out, int out_size, void* d_ws, size_t ws_size,
                              hipStream_t stream) {
    const float* x       = (const float*)d_in[0];
    const int*   kmer    = (const int*)  d_in[1];
    const int*   indices = (const int*)  d_in[2];
    const float* emb     = (const float*)d_in[3];
    const float* W1      = (const float*)d_in[4];
    const float* b1      = (const float*)d_in[5];
    const float* W2      = (const float*)d_in[6];
    const float* b2      = (const float*)d_in[7];
    const float* W3      = (const float*)d_in[8];
    const float* b3      = (const float*)d_in[9];
    const float* W4      = (const float*)d_in[10];
    const float* b4      = (const float*)d_in[11];

    float*  out = (float*)d_out;
    __bf16* h   = (__bf16*)d_ws;                       // [N,8] bf16 = 16 MB
    unsigned int* blob = (unsigned int*)((char*)d_ws + (16u << 20));  // 16 KB

    const int N = in_sizes[1];
    const int G = out_size;

    k_pack<<<1, 256, 0, stream>>>(W1, b1, W2, b2, blob);

    const int grid1 = (N + 511) / 512;    // 512 reads / block (4 waves x 8 x 16)
    k_readmlp<<<grid1, 256, 0, stream>>>(x, kmer, emb, blob, h, N);

    const int grid2 = (G + 31) / 32;
    k_site<<<grid2, 256, 0, stream>>>(h, indices, W3, b3, W4, b4, out, G);
}

// Round 8
// 158.128 us; speedup vs baseline: 1.2452x; 1.0032x over previous
//
#include <hip/hip_runtime.h>
#include <hip/hip_bf16.h>
#include <math.h>

#define HDIM 150
#define T1 4          // x-tiles (of 16 reads) per wave in k1

typedef __bf16 bf16x8 __attribute__((ext_vector_type(8)));
typedef __bf16 bf16x4 __attribute__((ext_vector_type(4)));
typedef float  f32x4  __attribute__((ext_vector_type(4)));

__device__ __forceinline__ void async_copy16(const void* g, void* l) {
    __builtin_amdgcn_global_load_lds(
        (const __attribute__((address_space(1))) void*)g,
        (__attribute__((address_space(3))) void*)l, 16, 0, 0);
}

// ---------------------------------------------------------------------------
// k_pack: one block precomputes the per-lane MFMA fragment blob shared by
// every k1 wave. R8: weights staged into LDS coalesced FIRST (R7 did ~32
// scattered dependent global loads/thread -> ~10us serial on the critical
// path); per-lane fragment math now reads LDS.
// Blob layout (uint4 view): tile i of lane L at blob4[i*64 + L].
// Per lane: dwords 0..39 = fA1[10] (bf16x8), 40..59 = fA2[5], 60..63 = breg.
// ---------------------------------------------------------------------------
__global__ void k_pack(const float* __restrict__ W1, const float* __restrict__ b1,
                       const float* __restrict__ W2, const float* __restrict__ b2,
                       unsigned int* __restrict__ blob)
{
    __shared__ float sW[4050];   // W1 [18][150] | b1 @2700 | W2 [150][8] @2850

    const int t    = threadIdx.x;
    const int lane = t & 63;
    const int c    = t >> 6;        // dword chunk 0..3
    const int m    = lane & 15;
    const int q    = lane >> 4;

    for (int e = t; e < 2700; e += 256) sW[e] = W1[e];
    for (int e = t; e < 150;  e += 256) sW[2700 + e] = b1[e];
    for (int e = t; e < 1200; e += 256) sW[2850 + e] = W2[e];
    __syncthreads();

    for (int d = c * 16; d < c * 16 + 16; ++d) {
        unsigned int word;
        if (d >= 60) {
            word = __float_as_uint(b2[(q & 1) * 4 + (d - 60)]);
        } else {
            float v0 = 0.f, v1 = 0.f;
            if (d < 40) {
                int n = d >> 2, j0 = (d & 3) * 2;
                // permuted hidden rows for the register relay:
                //   tile 2kt   row(4q+r) = hidden 32kt+8q+r
                //   tile 2kt+1 row(4q+r) = hidden 32kt+8q+4+r
                int hid = 32 * (n >> 1) + 8 * (m >> 2) + 4 * (n & 1) + (m & 3);
                if (hid < HDIM) {
                    int k0 = q * 8 + j0, k1 = k0 + 1;
                    v0 = (k0 < 18) ? sW[k0 * HDIM + hid] : (k0 == 18 ? sW[2700 + hid] : 0.f);
                    v1 = (k1 < 18) ? sW[k1 * HDIM + hid] : (k1 == 18 ? sW[2700 + hid] : 0.f);
                }
            } else {
                int kt = (d - 40) >> 2, j0 = ((d - 40) & 3) * 2;
                int k0 = kt * 32 + q * 8 + j0, k1 = k0 + 1;
                if (m < 8) {
                    v0 = (k0 < HDIM) ? sW[2850 + k0 * 8 + m] : 0.f;
                    v1 = (k1 < HDIM) ? sW[2850 + k1 * 8 + m] : 0.f;
                }
            }
            __bf16 h0 = (__bf16)v0, h1 = (__bf16)v1;
            unsigned short u0, u1;
            __builtin_memcpy(&u0, &h0, 2);
            __builtin_memcpy(&u1, &h1, 2);
            word = (unsigned int)u0 | ((unsigned int)u1 << 16);
        }
        blob[(d >> 2) * 256 + lane * 4 + (d & 3)] = word;
    }
}

// ---------------------------------------------------------------------------
// Kernel 1: per-read MLP via bf16 MFMA, register-relay layer1->layer2.
// Setup = 16 coalesced b128 loads of the precomputed fragment blob (L2-hot).
// x staged per wave via 4x global_load_lds (16B/lane) with a global-side XOR
// granule swizzle so the b128 fragment reads are bank-balanced.
// R8: T1 8->4 (16KB LDS/block, 2x blocks -> more TLP), in-loop h stores and
// single emb register pair (~18 fewer live VGPRs for iteration overlap).
// ---------------------------------------------------------------------------
__global__ __launch_bounds__(256, 3) void k_readmlp(
    const float* __restrict__ x, const int* __restrict__ kmer,
    const float* __restrict__ emb, const unsigned int* __restrict__ blob,
    __bf16* __restrict__ h, int Ntot)
{
    __shared__ __align__(16) char smem[16384];   // 4 waves x 4KB x-tiles

    const int tid  = threadIdx.x;
    const int lane = tid & 63;
    const int wv   = tid >> 6;
    const int m    = lane & 15;
    const int q    = lane >> 4;

    // ---- fragment blob: 16 coalesced dwordx4 loads ----
    uint4 B16[16];
    const uint4* bl = (const uint4*)blob;
#pragma unroll
    for (int i = 0; i < 16; ++i) B16[i] = bl[i * 64 + lane];
    const bf16x8* fr = (const bf16x8*)B16;       // fr[0..9]=fA1, fr[10..14]=fA2
    const float4 breg = ((const float4*)B16)[15];

    char* xbase = smem + wv * (T1 * 1024);
    const int waveBase = blockIdx.x * 256 + wv * 64;

    // ---- issue all 4 x-tile DMAs (lane fetches swizzled granule) ----
    const int gsw = lane ^ ((lane >> 3) & 7);
    const size_t xlimit = (size_t)Ntot * 64 - 16;
    const char* xg = (const char*)x;
#pragma unroll
    for (int t = 0; t < T1; ++t) {
        size_t off = (size_t)(waveBase + t * 16) * 64 + (size_t)gsw * 16;
        if (off > xlimit) off = xlimit;
        async_copy16(xg + off, xbase + t * 1024);
    }

    // ---- kmer -> emb for this wave's 64 reads, in registers ----
    const float2* emb2 = (const float2*)emb;
    int i0 = waveBase + lane; if (i0 >= Ntot) i0 = Ntot - 1;
    float2 e0 = emb2[kmer[i0]];

    const f32x4 zero = {0.f, 0.f, 0.f, 0.f};

#pragma unroll
    for (int t = 0; t < T1; ++t) {
        int src = (t << 4) + m;
        float ex = __shfl(e0.x, src);
        float ey = __shfl(e0.y, src);

        // input B-fragment: B[k = q*8+j][n = read m]
        bf16x8 bin;
        if (q < 2) {
            int g0 = 4 * m + 2 * q;
            int sx = (g0 >> 3) & 7;
            const char* tb = xbase + t * 1024;
            f32x4 u0 = *(const f32x4*)(tb + ((g0       ^ sx) << 4));
            f32x4 u1 = *(const f32x4*)(tb + (((g0 + 1) ^ sx) << 4));
            bin[0] = (__bf16)u0[0]; bin[1] = (__bf16)u0[1];
            bin[2] = (__bf16)u0[2]; bin[3] = (__bf16)u0[3];
            bin[4] = (__bf16)u1[0]; bin[5] = (__bf16)u1[1];
            bin[6] = (__bf16)u1[2]; bin[7] = (__bf16)u1[3];
        } else if (q == 2) {
            bin[0] = (__bf16)ex; bin[1] = (__bf16)ey;
            bin[2] = (__bf16)1.0f;   // bias-1 input at k==18
            bin[3] = (__bf16)0.f; bin[4] = (__bf16)0.f;
            bin[5] = (__bf16)0.f; bin[6] = (__bf16)0.f; bin[7] = (__bf16)0.f;
        } else {
#pragma unroll
            for (int j = 0; j < 8; ++j) bin[j] = (__bf16)0.f;
        }

        // layer1 tile-pair -> relu/pack -> layer2, all in registers.
        f32x4 c2a = zero, c2b = zero;
#pragma unroll
        for (int kt = 0; kt < 5; ++kt) {
            f32x4 ca = __builtin_amdgcn_mfma_f32_16x16x32_bf16(fr[2 * kt],     bin, zero, 0, 0, 0);
            f32x4 cb = __builtin_amdgcn_mfma_f32_16x16x32_bf16(fr[2 * kt + 1], bin, zero, 0, 0, 0);
            bf16x8 bh;
            bh[0] = (__bf16)fmaxf(ca[0], 0.f); bh[1] = (__bf16)fmaxf(ca[1], 0.f);
            bh[2] = (__bf16)fmaxf(ca[2], 0.f); bh[3] = (__bf16)fmaxf(ca[3], 0.f);
            bh[4] = (__bf16)fmaxf(cb[0], 0.f); bh[5] = (__bf16)fmaxf(cb[1], 0.f);
            bh[6] = (__bf16)fmaxf(cb[2], 0.f); bh[7] = (__bf16)fmaxf(cb[3], 0.f);
            if (kt & 1) c2b = __builtin_amdgcn_mfma_f32_16x16x32_bf16(fr[10 + kt], bh, c2b, 0, 0, 0);
            else        c2a = __builtin_amdgcn_mfma_f32_16x16x32_bf16(fr[10 + kt], bh, c2a, 0, 0, 0);
        }

        int r = waveBase + t * 16 + m;
        if (q < 2 && r < Ntot) {
            bf16x4 o;
            o[0] = (__bf16)fmaxf(c2a[0] + c2b[0] + breg.x, 0.f);
            o[1] = (__bf16)fmaxf(c2a[1] + c2b[1] + breg.y, 0.f);
            o[2] = (__bf16)fmaxf(c2a[2] + c2b[2] + breg.z, 0.f);
            o[3] = (__bf16)fmaxf(c2a[3] + c2b[3] + breg.w, 0.f);
            *(bf16x4*)(h + (size_t)r * 8 + q * 4) = o;   // fire-and-forget
        }
    }
}

// ---------------------------------------------------------------------------
// fully unrolled Batcher odd-even mergesort, n = 32
// ---------------------------------------------------------------------------
__device__ __forceinline__ void cswap(float& a, float& b) {
    float lo = fminf(a, b);
    float hi = fmaxf(a, b);
    a = lo; b = hi;
}

__device__ __forceinline__ void sort32(float v[32]) {
#pragma unroll
    for (int pp = 1; pp < 32; pp <<= 1) {
#pragma unroll
        for (int k = pp; k >= 1; k >>= 1) {
#pragma unroll
            for (int j = k & (pp - 1); j + k < 32; j += 2 * k) {
#pragma unroll
                for (int i = 0; i < k; ++i) {
                    if ((i + j) / (2 * pp) == (i + j + k) / (2 * pp))
                        cswap(v[i + j], v[i + j + k]);
                }
            }
        }
    }
}

// ---------------------------------------------------------------------------
// Kernel 2: per-site aggregation + head MLP (unchanged from R7).
// ---------------------------------------------------------------------------
__global__ __launch_bounds__(256) void k_site(
    const __bf16* __restrict__ hb, const int* __restrict__ indices,
    const float* __restrict__ W3, const float* __restrict__ b3,
    const float* __restrict__ W4, const float* __restrict__ b4,
    float* __restrict__ out, int Gtot)
{
    __shared__ int    sIdx[32 * 33];        // 4.2 KB
    __shared__ __align__(16) __bf16 sH[32 * 264];  // 16.9 KB
    __shared__ __bf16 sW3B[HDIM * 48];      // 14.4 KB
    __shared__ float  sB3[HDIM];
    __shared__ float  sW4[HDIM];
    __shared__ float  sAgg[32 * 44];        // 5.6 KB

    const int tid  = threadIdx.x;
    const int gblk = blockIdx.x * 32;

    for (int e = tid; e < 1024; e += 256) {
        int g = e >> 5;
        sIdx[g * 33 + (e & 31)] = (gblk + g < Gtot) ? indices[(size_t)gblk * 32 + e] : 0;
    }
    __syncthreads();

    for (int e = tid; e < 1024; e += 256) {
        int g = e >> 5, mm = e & 31;
        int r = sIdx[g * 33 + mm];
        *(uint4*)(&sH[g * 264 + mm * 8]) = *(const uint4*)(hb + (size_t)r * 8);
    }

    for (int e = tid; e < 40 * HDIM; e += 256) {
        int c = e / HDIM, j = e - c * HDIM;     // W3 row-major [40][150]
        sW3B[j * 48 + c] = (__bf16)W3[e];
    }
    for (int e = tid; e < HDIM; e += 256) { sB3[e] = b3[e]; sW4[e] = W4[e]; }
    __syncthreads();

    const int g = tid >> 3, p = tid & 7;
    {
        float v[32];
#pragma unroll
        for (int mm = 0; mm < 32; ++mm)
            v[mm] = (float)sH[g * 264 + mm * 8 + p];

        float sum = 0.f, sumsq = 0.f, mn = v[0], mx = v[0];
#pragma unroll
        for (int mm = 0; mm < 32; ++mm) {
            sum += v[mm];
            sumsq = fmaf(v[mm], v[mm], sumsq);
            mn = fminf(mn, v[mm]);
            mx = fmaxf(mx, v[mm]);
        }
        float mean = sum * (1.f / 32.f);
        float var  = fmaxf((sumsq - 32.f * mean * mean) * (1.f / 31.f), 0.f);
        sort32(v);
        sAgg[g * 44 + 0 * 8 + p] = mean;
        sAgg[g * 44 + 1 * 8 + p] = var;
        sAgg[g * 44 + 2 * 8 + p] = mn;
        sAgg[g * 44 + 3 * 8 + p] = v[15];   // lower median
        sAgg[g * 44 + 4 * 8 + p] = mx;
    }
    __syncthreads();

    float ag[40];
#pragma unroll
    for (int c4 = 0; c4 < 10; ++c4) {
        float4 tq = *(const float4*)(sAgg + g * 44 + c4 * 4);
        ag[c4 * 4 + 0] = tq.x; ag[c4 * 4 + 1] = tq.y;
        ag[c4 * 4 + 2] = tq.z; ag[c4 * 4 + 3] = tq.w;
    }

    float acc = 0.f;
    for (int j = p; j < HDIM; j += 8) {
        const __bf16* wr = sW3B + j * 48;
        float z = sB3[j];
#pragma unroll
        for (int c8 = 0; c8 < 5; ++c8) {
            bf16x8 w = *(const bf16x8*)(wr + c8 * 8);
#pragma unroll
            for (int u = 0; u < 8; ++u)
                z = fmaf(ag[c8 * 8 + u], (float)w[u], z);
        }
        z = fmaxf(z, 0.f);
        acc = fmaf(z, sW4[j], acc);
    }
    acc += __shfl_xor(acc, 1);
    acc += __shfl_xor(acc, 2);
    acc += __shfl_xor(acc, 4);

    if (p == 0 && gblk + g < Gtot) {
        float zf = acc + b4[0];
        out[gblk + g] = 1.f / (1.f + expf(-zf));
    }
}

// ---------------------------------------------------------------------------
extern "C" void kernel_launch(void* const* d_in, const int* in_sizes, int n_in,
                              void* d_out, int out_size, void* d_ws, size_t ws_size,
                              hipStream_t stream) {
    const float* x       = (const float*)d_in[0];
    const int*   kmer    = (const int*)  d_in[1];
    const int*   indices = (const int*)  d_in[2];
    const float* emb     = (const float*)d_in[3];
    const float* W1      = (const float*)d_in[4];
    const float* b1      = (const float*)d_in[5];
    const float* W2      = (const float*)d_in[6];
    const float* b2      = (const float*)d_in[7];
    const float* W3      = (const float*)d_in[8];
    const float* b3      = (const float*)d_in[9];
    const float* W4      = (const float*)d_in[10];
    const float* b4      = (const float*)d_in[11];

    float*  out = (float*)d_out;
    __bf16* h   = (__bf16*)d_ws;                       // [N,8] bf16 = 16 MB
    unsigned int* blob = (unsigned int*)((char*)d_ws + (16u << 20));  // 16 KB

    const int N = in_sizes[1];
    const int G = out_size;

    k_pack<<<1, 256, 0, stream>>>(W1, b1, W2, b2, blob);

    const int grid1 = (N + 255) / 256;    // 256 reads / block (4 waves x 4 x 16)
    k_readmlp<<<grid1, 256, 0, stream>>>(x, kmer, emb, blob, h, N);

    const int grid2 = (G + 31) / 32;
    k_site<<<grid2, 256, 0, stream>>>(h, indices, W3, b3, W4, b4, out, G);
}